// Round 8
// baseline (136.954 us; speedup 1.0000x reference)
//
#include <hip/hip_runtime.h>
#include <hip/hip_bf16.h>

#define N_NODES 50000
#define E_EDGES 800000
#define IN_DIM  128
#define OUT_DIM 64
#define MTILES  (N_NODES / 16)   // 3125, exact
#define NB      196              // coarse dst buckets (dst >> 8)
#define BCAP    6144             // bucket capacity: mean 4096, sd 64 -> +32 sigma
#define OVF_CAP 16384            // overflow list (expected use: 0)
#define NBLK_FC 196              // ceil(3125/16) fc blocks (16 tiles each, 4/wave)
#define NBLK_SA 625              // pass-A blocks
#define EPA     1280             // 800000/625 edges per pass-A block
#define ITER_A  5                // EPA / 256, uniform compile-time trip count

static_assert(N_NODES % 16 == 0, "16-row MFMA tiles");
static_assert(N_NODES < 65536, "node ids packed in 16 bits");
static_assert(NBLK_SA * EPA == E_EDGES, "pass-A blocks partition edges");
static_assert(EPA == ITER_A * 256, "uniform per-thread trip count");
static_assert(NB * 256 >= N_NODES, "buckets cover dst space");
static_assert(NBLK_FC * 16 >= MTILES, "fc blocks cover all tiles");

// ws: harness provides 256 MB; this layout uses 12.1 MB.

typedef __attribute__((ext_vector_type(8))) short bf16x8;
typedef __attribute__((ext_vector_type(4))) float f32x4;
typedef __attribute__((ext_vector_type(8))) unsigned short u16x8;

__device__ __forceinline__ unsigned short f32_to_bf16_rne(float f) {
    unsigned u = __float_as_uint(f);
    return (unsigned short)((u + 0x7FFFu + ((u >> 16) & 1u)) >> 16);
}
__device__ __forceinline__ float bf16_to_f32(unsigned short s) {
    return __uint_as_float(((unsigned)s) << 16);
}

// ---------------------------------------------------------------------------
// K1 (fused): blocks [0, NBLK_SA) = pass A (first: the latency-heavy sort
// blocks start at t=0, their tail overlaps fc); [NBLK_SA, +NBLK_FC) = fc.
// fc: 16 tiles/block, 4 per wave -- W loaded to LDS once per 256 output rows
// (was once per 64), B-fragments loaded once per wave and reused 4x.
// ---------------------------------------------------------------------------
__global__ __launch_bounds__(256) void gat_fc_scatter(
    const float* __restrict__ h,
    const float* __restrict__ Wfc,
    const float* __restrict__ bfc,
    const float* __restrict__ Watt,
    const float* __restrict__ batt,
    const int*   __restrict__ adj,
    unsigned short* __restrict__ z16,
    float* __restrict__ s1,
    float* __restrict__ s2,
    int*      __restrict__ gcnt,      // [NB+1] pre-zeroed; [NB] = ovf count
    unsigned* __restrict__ coarse,    // [NB*BCAP]
    unsigned* __restrict__ ovf)
{
    __shared__ short Wlds[OUT_DIM][IN_DIM + 8];   // 17.4 KB (fc blocks)

    if (blockIdx.x >= NBLK_SA) {
        // ------------------------------ fc ------------------------------
        for (int i = threadIdx.x; i < OUT_DIM * IN_DIM; i += 256) {
            const int o = i >> 7;            // /128
            const int k = i & 127;
            Wlds[o][k] = (short)f32_to_bf16_rne(Wfc[i]);
        }
        __syncthreads();

        const int lane  = threadIdx.x & 63;
        const int c     = lane & 15;          // A row / B col / C col
        const int q     = lane >> 4;          // quad
        const int wave  = threadIdx.x >> 6;
        const int tbase = (blockIdx.x - NBLK_SA) * 16 + wave * 4;

        // B fragments: B[k=t*32+q*8+j][n=f*16+c] = W[f*16+c][t*32+q*8+j]
        // loaded ONCE per wave, reused across 4 m-tiles
        bf16x8 B[4][4];
        #pragma unroll
        for (int t = 0; t < 4; ++t)
            #pragma unroll
            for (int f = 0; f < 4; ++f)
                B[t][f] = *(const bf16x8*)&Wlds[f * 16 + c][t * 32 + q * 8];

        const float batt0 = batt[0];
        float w1c[4], w2c[4], bv[4];
        #pragma unroll
        for (int f = 0; f < 4; ++f) {
            w1c[f] = Watt[f * 16 + c];
            w2c[f] = Watt[OUT_DIM + f * 16 + c];
            bv[f]  = bfc[f * 16 + c];
        }

        #pragma unroll
        for (int mi = 0; mi < 4; ++mi) {
            const int mtile = tbase + mi;
            if (mtile >= MTILES) break;       // wave-uniform
            const int n0 = mtile * 16;

            f32x4 acc[4] = {{0,0,0,0},{0,0,0,0},{0,0,0,0},{0,0,0,0}};
            const float* arow = h + (size_t)(n0 + c) * IN_DIM + q * 8;
            #pragma unroll
            for (int t = 0; t < 4; ++t) {
                float4 x0 = *(const float4*)(arow + t * 32);
                float4 x1 = *(const float4*)(arow + t * 32 + 4);
                bf16x8 a;
                a[0] = (short)f32_to_bf16_rne(x0.x);
                a[1] = (short)f32_to_bf16_rne(x0.y);
                a[2] = (short)f32_to_bf16_rne(x0.z);
                a[3] = (short)f32_to_bf16_rne(x0.w);
                a[4] = (short)f32_to_bf16_rne(x1.x);
                a[5] = (short)f32_to_bf16_rne(x1.y);
                a[6] = (short)f32_to_bf16_rne(x1.z);
                a[7] = (short)f32_to_bf16_rne(x1.w);
                #pragma unroll
                for (int f = 0; f < 4; ++f)
                    acc[f] = __builtin_amdgcn_mfma_f32_16x16x32_bf16(a, B[t][f], acc[f], 0, 0, 0);
            }

            float p1[4] = {0,0,0,0}, p2[4] = {0,0,0,0};
            #pragma unroll
            for (int f = 0; f < 4; ++f)
                #pragma unroll
                for (int r = 0; r < 4; ++r) {
                    const float v = acc[f][r] + bv[f];
                    z16[(size_t)(n0 + q * 4 + r) * OUT_DIM + f * 16 + c] = f32_to_bf16_rne(v);
                    p1[r] += v * w1c[f];
                    p2[r] += v * w2c[f];
                }
            #pragma unroll
            for (int r = 0; r < 4; ++r) {
                #pragma unroll
                for (int off = 1; off < 16; off <<= 1) {
                    p1[r] += __shfl_xor(p1[r], off, 64);
                    p2[r] += __shfl_xor(p2[r], off, 64);
                }
                if (c == 0) {
                    s1[n0 + q * 4 + r] = p1[r];
                    s2[n0 + q * 4 + r] = p2[r] + batt0;   // fold b_att in
                }
            }
        }
    } else {
        // --------------------------- pass A -----------------------------
        __shared__ unsigned el[EPA];                  // 5.1 KB, bucket-sorted
        __shared__ int sof[256];                      // histogram
        __shared__ int bexc[NB], lcur[NB], gbase[NB]; // 2.4 KB
        __shared__ int wsum[4];

        const int k    = blockIdx.x;                  // 0..624
        const int e0   = k * EPA;
        const int t    = threadIdx.x;
        const int lane = t & 63;
        const int w    = t >> 6;

        sof[t] = 0;
        __syncthreads();

        // 0) hoist this thread's 5 dst+src pairs into registers
        unsigned dv[ITER_A], sv[ITER_A];
        #pragma unroll
        for (int it = 0; it < ITER_A; ++it) {
            dv[it] = (unsigned)adj[E_EDGES + e0 + t + it * 256];
            sv[it] = (unsigned)adj[e0 + t + it * 256];
        }

        // 1) LDS histogram of this block's 1280 dsts
        #pragma unroll
        for (int it = 0; it < ITER_A; ++it)
            atomicAdd(&sof[dv[it] >> 8], 1);
        __syncthreads();

        // 2) wave-shfl exclusive scan (2 barriers)
        const int v = sof[t];
        int x = v;
        #pragma unroll
        for (int off = 1; off < 64; off <<= 1) {
            const int y = __shfl_up(x, off, 64);
            if (lane >= off) x += y;
        }
        if (lane == 63) wsum[w] = x;
        __syncthreads();
        int prefix = 0;
        #pragma unroll
        for (int ww = 0; ww < 4; ++ww)
            if (ww < w) prefix += wsum[ww];
        const int excl = x + prefix - v;
        if (t < NB) {
            bexc[t]  = excl;
            lcur[t]  = excl;
            gbase[t] = atomicAdd(&gcnt[t], v);   // 196 global atomics/block
        }
        __syncthreads();

        // 3) place edges bucket-sorted into LDS
        #pragma unroll
        for (int it = 0; it < ITER_A; ++it) {
            const int b = (int)(dv[it] >> 8);
            const int p = atomicAdd(&lcur[b], 1);
            el[p] = (dv[it] << 16) | sv[it];
        }
        __syncthreads();

        // 4) coalesced copy-out
        #pragma unroll
        for (int it = 0; it < ITER_A; ++it) {
            const int i = t + it * 256;
            const unsigned packed = el[i];
            const int b = (int)(packed >> 24);           // dst>>8
            const int pin = gbase[b] + (i - bexc[b]);
            if (pin < BCAP) {
                coarse[(size_t)b * BCAP + pin] = packed;
            } else {
                const int o = atomicAdd(&gcnt[NB], 1);
                if (o < OVF_CAP) ovf[o] = packed;
            }
        }
    }
}

// ---------------------------------------------------------------------------
// K2 (pass B, unchanged from round-5 best): one block per bucket, 512
// threads. Fused load+histogram; wave-shfl scan; dst-sort into LDS es[];
// coalesced linear write-back.
// ---------------------------------------------------------------------------
__global__ __launch_bounds__(512) void gat_binsort(
    unsigned* __restrict__ coarse,
    const int* __restrict__ gcnt,
    int* __restrict__ start, int* __restrict__ deg)
{
    __shared__ unsigned el[BCAP];                 // 24.6 KB unsorted
    __shared__ unsigned es[BCAP];                 // 24.6 KB dst-sorted
    __shared__ int hist[256], cur[256];           // 2 KB
    __shared__ int wsum[8];
    const int b    = blockIdx.x;
    const int t    = threadIdx.x;
    const int lane = t & 63;
    const int w    = t >> 6;
    const int nb   = min(gcnt[b], BCAP);

    if (t < 256) hist[t] = 0;
    __syncthreads();

    // fused load + histogram (one pass over the bucket)
    #pragma unroll 4
    for (int i = t; i < nb; i += 512) {
        const unsigned e = coarse[(size_t)b * BCAP + i];
        el[i] = e;
        atomicAdd(&hist[(e >> 16) & 255], 1);
    }
    __syncthreads();

    // wave-shfl exclusive scan over the 256 bins (threads >=256 carry 0)
    const int v = (t < 256) ? hist[t] : 0;
    int x = v;
    #pragma unroll
    for (int off = 1; off < 64; off <<= 1) {
        const int y = __shfl_up(x, off, 64);
        if (lane >= off) x += y;
    }
    if (lane == 63) wsum[w] = x;
    __syncthreads();
    int prefix = 0;
    #pragma unroll
    for (int ww = 0; ww < 8; ++ww)
        if (ww < w) prefix += wsum[ww];       // waves 4..7 sum zeros
    const int excl = x + prefix - v;
    if (t < 256) {
        cur[t] = excl;
        const int n = b * 256 + t;
        if (n < N_NODES) {
            start[n] = b * BCAP + excl;
            deg[n]   = v;
        }
    }
    __syncthreads();

    // dst-sort into LDS (scatter stays on-chip)
    #pragma unroll 4
    for (int i = t; i < nb; i += 512) {
        const unsigned e = el[i];
        const int p = atomicAdd(&cur[(e >> 16) & 255], 1);
        es[p] = e;
    }
    __syncthreads();

    // coalesced linear write-back
    #pragma unroll 4
    for (int i = t; i < nb; i += 512)
        coarse[(size_t)b * BCAP + i] = es[i];
}

// ---------------------------------------------------------------------------
// K3: gather (unchanged from round-5 best). 8 lanes/edge (ushort8 = 16B z
// load), 8 edge slots, 16-edge unroll (two independent chains).
// ---------------------------------------------------------------------------
__global__ __launch_bounds__(256) void gat_gather(
    const int* __restrict__ start, const int* __restrict__ deg,
    const unsigned* __restrict__ coarse, const int* __restrict__ gcnt,
    const unsigned* __restrict__ ovf,
    const float* __restrict__ s1, const float* __restrict__ s2,
    const unsigned short* __restrict__ z16,
    float* __restrict__ out)
{
    const int lane = threadIdx.x & 63;
    const int c    = lane & 7;        // feature group: features 8c..8c+7
    const int q    = lane >> 3;       // edge slot 0..7
    const int n    = blockIdx.x * 4 + (threadIdx.x >> 6);
    if (n >= N_NODES) return;

    const int m  = deg[n];
    const int jb = start[n];
    const float s2n = s2[n];                       // includes b_att

    float acc[8] = {0,0,0,0,0,0,0,0};
    int j = 0;
    for (; j + 16 <= m; j += 16) {
        const int srcA = (int)(coarse[jb + j + q] & 0xFFFFu);
        const int srcB = (int)(coarse[jb + j + 8 + q] & 0xFFFFu);
        float aA = s1[srcA] + s2n;
        float aB = s1[srcB] + s2n;
        aA = (aA > 0.f) ? aA : 0.01f * aA;
        aB = (aB > 0.f) ? aB : 0.01f * aB;
        const u16x8 zA = *(const u16x8*)&z16[(size_t)srcA * OUT_DIM + 8 * c];
        const u16x8 zB = *(const u16x8*)&z16[(size_t)srcB * OUT_DIM + 8 * c];
        #pragma unroll
        for (int u = 0; u < 8; ++u) acc[u] += aA * bf16_to_f32(zA[u]);
        #pragma unroll
        for (int u = 0; u < 8; ++u) acc[u] += aB * bf16_to_f32(zB[u]);
    }
    for (; j + 8 <= m; j += 8) {
        const int src = (int)(coarse[jb + j + q] & 0xFFFFu);
        float a = s1[src] + s2n;
        a = (a > 0.f) ? a : 0.01f * a;
        const u16x8 zz = *(const u16x8*)&z16[(size_t)src * OUT_DIM + 8 * c];
        #pragma unroll
        for (int u = 0; u < 8; ++u) acc[u] += a * bf16_to_f32(zz[u]);
    }
    if (q < m - j) {
        const int src = (int)(coarse[jb + j + q] & 0xFFFFu);
        float a = s1[src] + s2n;
        a = (a > 0.f) ? a : 0.01f * a;
        const u16x8 zz = *(const u16x8*)&z16[(size_t)src * OUT_DIM + 8 * c];
        #pragma unroll
        for (int u = 0; u < 8; ++u) acc[u] += a * bf16_to_f32(zz[u]);
    }

    // self-service overflow (expected 0)
    const int novf = min(gcnt[NB], OVF_CAP);
    for (int base = 0; base < novf; base += 8) {
        const int idx = base + q;
        const unsigned packed = (idx < novf) ? ovf[idx] : 0xFFFFFFFFu;
        const bool valid = (idx < novf) && ((packed >> 16) == (unsigned)n);
        const int src = valid ? (int)(packed & 0xFFFFu) : 0;
        float a = s1[src] + s2n;
        a = (a > 0.f) ? a : 0.01f * a;
        a = valid ? a : 0.f;
        const u16x8 zz = *(const u16x8*)&z16[(size_t)src * OUT_DIM + 8 * c];
        #pragma unroll
        for (int u = 0; u < 8; ++u) acc[u] += a * bf16_to_f32(zz[u]);
    }

    // combine the 8 edge slots (slot index in lane bits 3..5)
    #pragma unroll
    for (int u = 0; u < 8; ++u) {
        acc[u] += __shfl_xor(acc[u], 8, 64);
        acc[u] += __shfl_xor(acc[u], 16, 64);
        acc[u] += __shfl_xor(acc[u], 32, 64);
    }

    if (q == 0) {
        float4 lo = make_float4(acc[0], acc[1], acc[2], acc[3]);
        float4 hi = make_float4(acc[4], acc[5], acc[6], acc[7]);
        *(float4*)&out[(size_t)n * OUT_DIM + 8 * c]     = lo;
        *(float4*)&out[(size_t)n * OUT_DIM + 8 * c + 4] = hi;
    }
}

extern "C" void kernel_launch(void* const* d_in, const int* in_sizes, int n_in,
                              void* d_out, int out_size, void* d_ws, size_t ws_size,
                              hipStream_t stream)
{
    const int*   adj  = (const int*)  d_in[0];   // (2, E)
    const float* h    = (const float*)d_in[1];   // (N, 128)
    const float* Wfc  = (const float*)d_in[2];   // (64, 128)
    const float* bfc  = (const float*)d_in[3];   // (64,)
    const float* Watt = (const float*)d_in[4];   // (1, 128)
    const float* batt = (const float*)d_in[5];   // (1,)
    float* out = (float*)d_out;                  // (N, 64)

    // ws layout (12.1 MB): z16[N*64] u16 | s1[N] | s2[N] | start[N] | deg[N]
    // | gcnt[NB+1] ([NB]=ovf count) | ovf[OVF_CAP] u32 | coarse[NB*BCAP] u32
    unsigned short* z16 = (unsigned short*)d_ws;
    float* s1    = (float*)(z16 + (size_t)N_NODES * OUT_DIM);
    float* s2    = s1 + N_NODES;
    int*   start = (int*)(s2 + N_NODES);
    int*   deg   = start + N_NODES;
    int*   gcnt  = deg + N_NODES;
    unsigned* ovf    = (unsigned*)(gcnt + NB + 1);
    unsigned* coarse = ovf + OVF_CAP;

    hipMemsetAsync(gcnt, 0, (NB + 1) * sizeof(int), stream);

    gat_fc_scatter<<<NBLK_SA + NBLK_FC, 256, 0, stream>>>(
        h, Wfc, bfc, Watt, batt, adj, z16, s1, s2, gcnt, coarse, ovf);
    gat_binsort<<<NB, 512, 0, stream>>>(coarse, gcnt, start, deg);
    gat_gather<<<(N_NODES + 3) / 4, 256, 0, stream>>>(
        start, deg, coarse, gcnt, ovf, s1, s2, z16, out);
}

// Round 9
// 130.785 us; speedup vs baseline: 1.0472x; 1.0472x over previous
//
#include <hip/hip_runtime.h>
#include <hip/hip_bf16.h>

#define N_NODES 50000
#define E_EDGES 800000
#define IN_DIM  128
#define OUT_DIM 64
#define MTILES  (N_NODES / 16)   // 3125, exact
#define NB      196              // coarse dst buckets (dst >> 8)
#define BCAP    6144             // bucket capacity: mean 4096, sd 64 -> +32 sigma
#define OVF_CAP 16384            // overflow list (expected use: 0)
#define NBLK_FC 782              // ceil(3125/4) fc blocks (4 tiles each, 1/wave)
#define NBLK_SA 625              // pass-A blocks
#define EPA     1280             // 800000/625 edges per pass-A block
#define ITER_A  5                // EPA / 256, uniform compile-time trip count

static_assert(N_NODES % 16 == 0, "16-row MFMA tiles");
static_assert(N_NODES < 65536, "node ids packed in 16 bits");
static_assert(NBLK_SA * EPA == E_EDGES, "pass-A blocks partition edges");
static_assert(EPA == ITER_A * 256, "uniform per-thread trip count");
static_assert(NB * 256 >= N_NODES, "buckets cover dst space");

// ws: harness provides 256 MB; this layout uses 12.1 MB.

typedef __attribute__((ext_vector_type(8))) short bf16x8;
typedef __attribute__((ext_vector_type(4))) float f32x4;
typedef __attribute__((ext_vector_type(4))) unsigned short u16x4;

__device__ __forceinline__ unsigned short f32_to_bf16_rne(float f) {
    unsigned u = __float_as_uint(f);
    return (unsigned short)((u + 0x7FFFu + ((u >> 16) & 1u)) >> 16);
}
__device__ __forceinline__ float bf16_to_f32(unsigned short s) {
    return __uint_as_float(((unsigned)s) << 16);
}

// ---------------------------------------------------------------------------
// K1 (fused, round-5 form): blocks [0, NBLK_FC) = MFMA fc (1 tile/wave --
// round-8 showed 4 serial tiles/wave regresses); [NBLK_FC, +NBLK_SA) = pass A
// (1280 edges/block, operands hoisted, bucket-sorted in LDS, wave-shfl scan,
// coalesced copy-out).
// ---------------------------------------------------------------------------
__global__ __launch_bounds__(256) void gat_fc_scatter(
    const float* __restrict__ h,
    const float* __restrict__ Wfc,
    const float* __restrict__ bfc,
    const float* __restrict__ Watt,
    const float* __restrict__ batt,
    const int*   __restrict__ adj,
    unsigned short* __restrict__ z16,
    float* __restrict__ s1,
    float* __restrict__ s2,
    int*      __restrict__ gcnt,      // [NB+1] pre-zeroed; [NB] = ovf count
    unsigned* __restrict__ coarse,    // [NB*BCAP]
    unsigned* __restrict__ ovf)
{
    __shared__ short Wlds[OUT_DIM][IN_DIM + 8];   // 17.4 KB (fc blocks)

    if (blockIdx.x < NBLK_FC) {
        // ------------------------------ fc ------------------------------
        for (int i = threadIdx.x; i < OUT_DIM * IN_DIM; i += 256) {
            const int o = i >> 7;            // /128
            const int k = i & 127;
            Wlds[o][k] = (short)f32_to_bf16_rne(Wfc[i]);
        }
        __syncthreads();

        const int lane  = threadIdx.x & 63;
        const int c     = lane & 15;          // A row / B col / C col
        const int q     = lane >> 4;          // quad
        const int mtile = blockIdx.x * 4 + (threadIdx.x >> 6);
        if (mtile >= MTILES) return;
        const int n0 = mtile * 16;

        // B fragments: B[k=t*32+q*8+j][n=f*16+c] = W[f*16+c][t*32+q*8+j]
        bf16x8 B[4][4];
        #pragma unroll
        for (int t = 0; t < 4; ++t)
            #pragma unroll
            for (int f = 0; f < 4; ++f)
                B[t][f] = *(const bf16x8*)&Wlds[f * 16 + c][t * 32 + q * 8];

        f32x4 acc[4] = {{0,0,0,0},{0,0,0,0},{0,0,0,0},{0,0,0,0}};

        const float* arow = h + (size_t)(n0 + c) * IN_DIM + q * 8;
        #pragma unroll
        for (int t = 0; t < 4; ++t) {
            float4 x0 = *(const float4*)(arow + t * 32);
            float4 x1 = *(const float4*)(arow + t * 32 + 4);
            bf16x8 a;
            a[0] = (short)f32_to_bf16_rne(x0.x);
            a[1] = (short)f32_to_bf16_rne(x0.y);
            a[2] = (short)f32_to_bf16_rne(x0.z);
            a[3] = (short)f32_to_bf16_rne(x0.w);
            a[4] = (short)f32_to_bf16_rne(x1.x);
            a[5] = (short)f32_to_bf16_rne(x1.y);
            a[6] = (short)f32_to_bf16_rne(x1.z);
            a[7] = (short)f32_to_bf16_rne(x1.w);
            #pragma unroll
            for (int f = 0; f < 4; ++f)
                acc[f] = __builtin_amdgcn_mfma_f32_16x16x32_bf16(a, B[t][f], acc[f], 0, 0, 0);
        }

        const float batt0 = batt[0];
        float w1c[4], w2c[4], bv[4];
        #pragma unroll
        for (int f = 0; f < 4; ++f) {
            w1c[f] = Watt[f * 16 + c];
            w2c[f] = Watt[OUT_DIM + f * 16 + c];
            bv[f]  = bfc[f * 16 + c];
        }
        float p1[4] = {0,0,0,0}, p2[4] = {0,0,0,0};
        #pragma unroll
        for (int f = 0; f < 4; ++f)
            #pragma unroll
            for (int r = 0; r < 4; ++r) {
                const float v = acc[f][r] + bv[f];
                z16[(size_t)(n0 + q * 4 + r) * OUT_DIM + f * 16 + c] = f32_to_bf16_rne(v);
                p1[r] += v * w1c[f];
                p2[r] += v * w2c[f];
            }
        #pragma unroll
        for (int r = 0; r < 4; ++r) {
            #pragma unroll
            for (int off = 1; off < 16; off <<= 1) {
                p1[r] += __shfl_xor(p1[r], off, 64);
                p2[r] += __shfl_xor(p2[r], off, 64);
            }
            if (c == 0) {
                s1[n0 + q * 4 + r] = p1[r];
                s2[n0 + q * 4 + r] = p2[r] + batt0;   // fold b_att in
            }
        }
    } else {
        // --------------------------- pass A -----------------------------
        __shared__ unsigned el[EPA];                  // 5.1 KB, bucket-sorted
        __shared__ int sof[256];                      // histogram
        __shared__ int bexc[NB], lcur[NB], gbase[NB]; // 2.4 KB
        __shared__ int wsum[4];

        const int k    = blockIdx.x - NBLK_FC;        // 0..624
        const int e0   = k * EPA;
        const int t    = threadIdx.x;
        const int lane = t & 63;
        const int w    = t >> 6;

        sof[t] = 0;
        __syncthreads();

        // 0) hoist this thread's 5 dst+src pairs into registers
        unsigned dv[ITER_A], sv[ITER_A];
        #pragma unroll
        for (int it = 0; it < ITER_A; ++it) {
            dv[it] = (unsigned)adj[E_EDGES + e0 + t + it * 256];
            sv[it] = (unsigned)adj[e0 + t + it * 256];
        }

        // 1) LDS histogram of this block's 1280 dsts
        #pragma unroll
        for (int it = 0; it < ITER_A; ++it)
            atomicAdd(&sof[dv[it] >> 8], 1);
        __syncthreads();

        // 2) wave-shfl exclusive scan (2 barriers)
        const int v = sof[t];
        int x = v;
        #pragma unroll
        for (int off = 1; off < 64; off <<= 1) {
            const int y = __shfl_up(x, off, 64);
            if (lane >= off) x += y;
        }
        if (lane == 63) wsum[w] = x;
        __syncthreads();
        int prefix = 0;
        #pragma unroll
        for (int ww = 0; ww < 4; ++ww)
            if (ww < w) prefix += wsum[ww];
        const int excl = x + prefix - v;
        if (t < NB) {
            bexc[t]  = excl;
            lcur[t]  = excl;
            gbase[t] = atomicAdd(&gcnt[t], v);   // 196 global atomics/block
        }
        __syncthreads();

        // 3) place edges bucket-sorted into LDS
        #pragma unroll
        for (int it = 0; it < ITER_A; ++it) {
            const int b = (int)(dv[it] >> 8);
            const int p = atomicAdd(&lcur[b], 1);
            el[p] = (dv[it] << 16) | sv[it];
        }
        __syncthreads();

        // 4) coalesced copy-out
        #pragma unroll
        for (int it = 0; it < ITER_A; ++it) {
            const int i = t + it * 256;
            const unsigned packed = el[i];
            const int b = (int)(packed >> 24);           // dst>>8
            const int pin = gbase[b] + (i - bexc[b]);
            if (pin < BCAP) {
                coarse[(size_t)b * BCAP + pin] = packed;
            } else {
                const int o = atomicAdd(&gcnt[NB], 1);
                if (o < OVF_CAP) ovf[o] = packed;
            }
        }
    }
}

// ---------------------------------------------------------------------------
// K2 (pass B, round-5 form): one block per bucket, 512 threads. Fused
// load+histogram; wave-shfl scan; dst-sort into LDS es[]; coalesced linear
// write-back.
// ---------------------------------------------------------------------------
__global__ __launch_bounds__(512) void gat_binsort(
    unsigned* __restrict__ coarse,
    const int* __restrict__ gcnt,
    int* __restrict__ start, int* __restrict__ deg)
{
    __shared__ unsigned el[BCAP];                 // 24.6 KB unsorted
    __shared__ unsigned es[BCAP];                 // 24.6 KB dst-sorted
    __shared__ int hist[256], cur[256];           // 2 KB
    __shared__ int wsum[8];
    const int b    = blockIdx.x;
    const int t    = threadIdx.x;
    const int lane = t & 63;
    const int w    = t >> 6;
    const int nb   = min(gcnt[b], BCAP);

    if (t < 256) hist[t] = 0;
    __syncthreads();

    // fused load + histogram (one pass over the bucket)
    #pragma unroll 4
    for (int i = t; i < nb; i += 512) {
        const unsigned e = coarse[(size_t)b * BCAP + i];
        el[i] = e;
        atomicAdd(&hist[(e >> 16) & 255], 1);
    }
    __syncthreads();

    // wave-shfl exclusive scan over the 256 bins (threads >=256 carry 0)
    const int v = (t < 256) ? hist[t] : 0;
    int x = v;
    #pragma unroll
    for (int off = 1; off < 64; off <<= 1) {
        const int y = __shfl_up(x, off, 64);
        if (lane >= off) x += y;
    }
    if (lane == 63) wsum[w] = x;
    __syncthreads();
    int prefix = 0;
    #pragma unroll
    for (int ww = 0; ww < 8; ++ww)
        if (ww < w) prefix += wsum[ww];       // waves 4..7 sum zeros
    const int excl = x + prefix - v;
    if (t < 256) {
        cur[t] = excl;
        const int n = b * 256 + t;
        if (n < N_NODES) {
            start[n] = b * BCAP + excl;
            deg[n]   = v;
        }
    }
    __syncthreads();

    // dst-sort into LDS (scatter stays on-chip)
    #pragma unroll 4
    for (int i = t; i < nb; i += 512) {
        const unsigned e = el[i];
        const int p = atomicAdd(&cur[(e >> 16) & 255], 1);
        es[p] = e;
    }
    __syncthreads();

    // coalesced linear write-back
    #pragma unroll 4
    for (int i = t; i < nb; i += 512)
        coarse[(size_t)b * BCAP + i] = es[i];
}

// ---------------------------------------------------------------------------
// K3: gather, NEW lane geometry: 16 lanes/edge (4 features each), 4 edge
// slots. Per node (deg~16): slot-combine drops from 24 shfl+24 add (8-slot
// form) to 8 shfl+8 add; inner loop keeps two independent load chains
// (8 edges in flight). Store: lanes q==0 write out as 16 contiguous float4.
// ---------------------------------------------------------------------------
__global__ __launch_bounds__(256) void gat_gather(
    const int* __restrict__ start, const int* __restrict__ deg,
    const unsigned* __restrict__ coarse, const int* __restrict__ gcnt,
    const unsigned* __restrict__ ovf,
    const float* __restrict__ s1, const float* __restrict__ s2,
    const unsigned short* __restrict__ z16,
    float* __restrict__ out)
{
    const int lane = threadIdx.x & 63;
    const int c    = lane & 15;       // feature group: features 4c..4c+3
    const int q    = lane >> 4;       // edge slot 0..3
    const int n    = blockIdx.x * 4 + (threadIdx.x >> 6);
    if (n >= N_NODES) return;

    const int m  = deg[n];
    const int jb = start[n];
    const float s2n = s2[n];                       // includes b_att

    float acc[4] = {0,0,0,0};
    int j = 0;
    for (; j + 8 <= m; j += 8) {
        const int srcA = (int)(coarse[jb + j + q] & 0xFFFFu);
        const int srcB = (int)(coarse[jb + j + 4 + q] & 0xFFFFu);
        float aA = s1[srcA] + s2n;
        float aB = s1[srcB] + s2n;
        aA = (aA > 0.f) ? aA : 0.01f * aA;
        aB = (aB > 0.f) ? aB : 0.01f * aB;
        const u16x4 zA = *(const u16x4*)&z16[(size_t)srcA * OUT_DIM + 4 * c];
        const u16x4 zB = *(const u16x4*)&z16[(size_t)srcB * OUT_DIM + 4 * c];
        #pragma unroll
        for (int u = 0; u < 4; ++u) acc[u] += aA * bf16_to_f32(zA[u]);
        #pragma unroll
        for (int u = 0; u < 4; ++u) acc[u] += aB * bf16_to_f32(zB[u]);
    }
    for (; j + 4 <= m; j += 4) {
        const int src = (int)(coarse[jb + j + q] & 0xFFFFu);
        float a = s1[src] + s2n;
        a = (a > 0.f) ? a : 0.01f * a;
        const u16x4 zz = *(const u16x4*)&z16[(size_t)src * OUT_DIM + 4 * c];
        #pragma unroll
        for (int u = 0; u < 4; ++u) acc[u] += a * bf16_to_f32(zz[u]);
    }
    if (q < m - j) {
        const int src = (int)(coarse[jb + j + q] & 0xFFFFu);
        float a = s1[src] + s2n;
        a = (a > 0.f) ? a : 0.01f * a;
        const u16x4 zz = *(const u16x4*)&z16[(size_t)src * OUT_DIM + 4 * c];
        #pragma unroll
        for (int u = 0; u < 4; ++u) acc[u] += a * bf16_to_f32(zz[u]);
    }

    // self-service overflow (expected 0)
    const int novf = min(gcnt[NB], OVF_CAP);
    for (int base = 0; base < novf; base += 4) {
        const int idx = base + q;
        const unsigned packed = (idx < novf) ? ovf[idx] : 0xFFFFFFFFu;
        const bool valid = (idx < novf) && ((packed >> 16) == (unsigned)n);
        const int src = valid ? (int)(packed & 0xFFFFu) : 0;
        float a = s1[src] + s2n;
        a = (a > 0.f) ? a : 0.01f * a;
        a = valid ? a : 0.f;
        const u16x4 zz = *(const u16x4*)&z16[(size_t)src * OUT_DIM + 4 * c];
        #pragma unroll
        for (int u = 0; u < 4; ++u) acc[u] += a * bf16_to_f32(zz[u]);
    }

    // combine the 4 edge slots (slot index in lane bits 4..5)
    #pragma unroll
    for (int u = 0; u < 4; ++u) {
        acc[u] += __shfl_xor(acc[u], 16, 64);
        acc[u] += __shfl_xor(acc[u], 32, 64);
    }

    if (q == 0) {
        float4 vv = make_float4(acc[0], acc[1], acc[2], acc[3]);
        *(float4*)&out[(size_t)n * OUT_DIM + 4 * c] = vv;
    }
}

extern "C" void kernel_launch(void* const* d_in, const int* in_sizes, int n_in,
                              void* d_out, int out_size, void* d_ws, size_t ws_size,
                              hipStream_t stream)
{
    const int*   adj  = (const int*)  d_in[0];   // (2, E)
    const float* h    = (const float*)d_in[1];   // (N, 128)
    const float* Wfc  = (const float*)d_in[2];   // (64, 128)
    const float* bfc  = (const float*)d_in[3];   // (64,)
    const float* Watt = (const float*)d_in[4];   // (1, 128)
    const float* batt = (const float*)d_in[5];   // (1,)
    float* out = (float*)d_out;                  // (N, 64)

    // ws layout (12.1 MB): z16[N*64] u16 | s1[N] | s2[N] | start[N] | deg[N]
    // | gcnt[NB+1] ([NB]=ovf count) | ovf[OVF_CAP] u32 | coarse[NB*BCAP] u32
    unsigned short* z16 = (unsigned short*)d_ws;
    float* s1    = (float*)(z16 + (size_t)N_NODES * OUT_DIM);
    float* s2    = s1 + N_NODES;
    int*   start = (int*)(s2 + N_NODES);
    int*   deg   = start + N_NODES;
    int*   gcnt  = deg + N_NODES;
    unsigned* ovf    = (unsigned*)(gcnt + NB + 1);
    unsigned* coarse = ovf + OVF_CAP;

    hipMemsetAsync(gcnt, 0, (NB + 1) * sizeof(int), stream);

    gat_fc_scatter<<<NBLK_FC + NBLK_SA, 256, 0, stream>>>(
        h, Wfc, bfc, Watt, batt, adj, z16, s1, s2, gcnt, coarse, ovf);
    gat_binsort<<<NB, 512, 0, stream>>>(coarse, gcnt, start, deg);
    gat_gather<<<(N_NODES + 3) / 4, 256, 0, stream>>>(
        start, deg, coarse, gcnt, ovf, s1, s2, z16, out);
}

// Round 10
// 127.151 us; speedup vs baseline: 1.0771x; 1.0286x over previous
//
#include <hip/hip_runtime.h>
#include <hip/hip_bf16.h>

#define N_NODES 50000
#define E_EDGES 800000
#define IN_DIM  128
#define OUT_DIM 64
#define MTILES  (N_NODES / 16)   // 3125, exact
#define NB      196              // coarse dst buckets (dst >> 8)
#define BCAP    6144             // bucket capacity: mean 4096, sd 64 -> +32 sigma
#define OVF_CAP 16384            // overflow list (expected use: 0)
#define NBLK_FC 782              // ceil(3125/4) fc blocks (4 tiles each)
#define NBLK_SA 625              // pass-A blocks
#define EPA     1280             // 800000/625 edges per pass-A block
#define ITER_A  5                // EPA / 256, uniform compile-time trip count

static_assert(N_NODES % 16 == 0, "16-row MFMA tiles");
static_assert(N_NODES < 65536, "node ids packed in 16 bits");
static_assert(NBLK_SA * EPA == E_EDGES, "pass-A blocks partition edges");
static_assert(EPA == ITER_A * 256, "uniform per-thread trip count");
static_assert(NB * 256 >= N_NODES, "buckets cover dst space");

// ws: harness provides 256 MB; this layout uses 12.1 MB.

typedef __attribute__((ext_vector_type(8))) short bf16x8;
typedef __attribute__((ext_vector_type(4))) float f32x4;
typedef __attribute__((ext_vector_type(8))) unsigned short u16x8;

__device__ __forceinline__ unsigned short f32_to_bf16_rne(float f) {
    unsigned u = __float_as_uint(f);
    return (unsigned short)((u + 0x7FFFu + ((u >> 16) & 1u)) >> 16);
}
__device__ __forceinline__ float bf16_to_f32(unsigned short s) {
    return __uint_as_float(((unsigned)s) << 16);
}

// ---------------------------------------------------------------------------
// K1 (fused): blocks [0, NBLK_FC) = MFMA fc; blocks [NBLK_FC, +NBLK_SA) = pass A.
// Pass A: 1280 edges/block = 5 uniform iters/thread, operands hoisted to
// registers, bucket-sorted in LDS, wave-shfl scan (2 barriers), coalesced
// copy-out. This is the session's measured-best configuration (round 5).
// ---------------------------------------------------------------------------
__global__ __launch_bounds__(256) void gat_fc_scatter(
    const float* __restrict__ h,
    const float* __restrict__ Wfc,
    const float* __restrict__ bfc,
    const float* __restrict__ Watt,
    const float* __restrict__ batt,
    const int*   __restrict__ adj,
    unsigned short* __restrict__ z16,
    float* __restrict__ s1,
    float* __restrict__ s2,
    int*      __restrict__ gcnt,      // [NB+1] pre-zeroed; [NB] = ovf count
    unsigned* __restrict__ coarse,    // [NB*BCAP]
    unsigned* __restrict__ ovf)
{
    __shared__ short Wlds[OUT_DIM][IN_DIM + 8];   // 17.4 KB (fc blocks)

    if (blockIdx.x < NBLK_FC) {
        // ------------------------------ fc ------------------------------
        for (int i = threadIdx.x; i < OUT_DIM * IN_DIM; i += 256) {
            const int o = i >> 7;            // /128
            const int k = i & 127;
            Wlds[o][k] = (short)f32_to_bf16_rne(Wfc[i]);
        }
        __syncthreads();

        const int lane  = threadIdx.x & 63;
        const int c     = lane & 15;          // A row / B col / C col
        const int q     = lane >> 4;          // quad
        const int mtile = blockIdx.x * 4 + (threadIdx.x >> 6);
        if (mtile >= MTILES) return;
        const int n0 = mtile * 16;

        // B fragments: B[k=t*32+q*8+j][n=f*16+c] = W[f*16+c][t*32+q*8+j]
        bf16x8 B[4][4];
        #pragma unroll
        for (int t = 0; t < 4; ++t)
            #pragma unroll
            for (int f = 0; f < 4; ++f)
                B[t][f] = *(const bf16x8*)&Wlds[f * 16 + c][t * 32 + q * 8];

        f32x4 acc[4] = {{0,0,0,0},{0,0,0,0},{0,0,0,0},{0,0,0,0}};

        const float* arow = h + (size_t)(n0 + c) * IN_DIM + q * 8;
        #pragma unroll
        for (int t = 0; t < 4; ++t) {
            float4 x0 = *(const float4*)(arow + t * 32);
            float4 x1 = *(const float4*)(arow + t * 32 + 4);
            bf16x8 a;
            a[0] = (short)f32_to_bf16_rne(x0.x);
            a[1] = (short)f32_to_bf16_rne(x0.y);
            a[2] = (short)f32_to_bf16_rne(x0.z);
            a[3] = (short)f32_to_bf16_rne(x0.w);
            a[4] = (short)f32_to_bf16_rne(x1.x);
            a[5] = (short)f32_to_bf16_rne(x1.y);
            a[6] = (short)f32_to_bf16_rne(x1.z);
            a[7] = (short)f32_to_bf16_rne(x1.w);
            #pragma unroll
            for (int f = 0; f < 4; ++f)
                acc[f] = __builtin_amdgcn_mfma_f32_16x16x32_bf16(a, B[t][f], acc[f], 0, 0, 0);
        }

        const float batt0 = batt[0];
        float w1c[4], w2c[4], bv[4];
        #pragma unroll
        for (int f = 0; f < 4; ++f) {
            w1c[f] = Watt[f * 16 + c];
            w2c[f] = Watt[OUT_DIM + f * 16 + c];
            bv[f]  = bfc[f * 16 + c];
        }
        float p1[4] = {0,0,0,0}, p2[4] = {0,0,0,0};
        #pragma unroll
        for (int f = 0; f < 4; ++f)
            #pragma unroll
            for (int r = 0; r < 4; ++r) {
                const float v = acc[f][r] + bv[f];
                z16[(size_t)(n0 + q * 4 + r) * OUT_DIM + f * 16 + c] = f32_to_bf16_rne(v);
                p1[r] += v * w1c[f];
                p2[r] += v * w2c[f];
            }
        #pragma unroll
        for (int r = 0; r < 4; ++r) {
            #pragma unroll
            for (int off = 1; off < 16; off <<= 1) {
                p1[r] += __shfl_xor(p1[r], off, 64);
                p2[r] += __shfl_xor(p2[r], off, 64);
            }
            if (c == 0) {
                s1[n0 + q * 4 + r] = p1[r];
                s2[n0 + q * 4 + r] = p2[r] + batt0;   // fold b_att in
            }
        }
    } else {
        // --------------------------- pass A -----------------------------
        __shared__ unsigned el[EPA];                  // 5.1 KB, bucket-sorted
        __shared__ int sof[256];                      // histogram
        __shared__ int bexc[NB], lcur[NB], gbase[NB]; // 2.4 KB
        __shared__ int wsum[4];

        const int k    = blockIdx.x - NBLK_FC;        // 0..624
        const int e0   = k * EPA;
        const int t    = threadIdx.x;
        const int lane = t & 63;
        const int w    = t >> 6;

        sof[t] = 0;
        __syncthreads();

        // 0) hoist this thread's 5 dst+src pairs into registers
        unsigned dv[ITER_A], sv[ITER_A];
        #pragma unroll
        for (int it = 0; it < ITER_A; ++it) {
            dv[it] = (unsigned)adj[E_EDGES + e0 + t + it * 256];
            sv[it] = (unsigned)adj[e0 + t + it * 256];
        }

        // 1) LDS histogram of this block's 1280 dsts
        #pragma unroll
        for (int it = 0; it < ITER_A; ++it)
            atomicAdd(&sof[dv[it] >> 8], 1);
        __syncthreads();

        // 2) wave-shfl exclusive scan (2 barriers)
        const int v = sof[t];
        int x = v;
        #pragma unroll
        for (int off = 1; off < 64; off <<= 1) {
            const int y = __shfl_up(x, off, 64);
            if (lane >= off) x += y;
        }
        if (lane == 63) wsum[w] = x;
        __syncthreads();
        int prefix = 0;
        #pragma unroll
        for (int ww = 0; ww < 4; ++ww)
            if (ww < w) prefix += wsum[ww];
        const int excl = x + prefix - v;
        if (t < NB) {
            bexc[t]  = excl;
            lcur[t]  = excl;
            gbase[t] = atomicAdd(&gcnt[t], v);   // 196 global atomics/block
        }
        __syncthreads();

        // 3) place edges bucket-sorted into LDS
        #pragma unroll
        for (int it = 0; it < ITER_A; ++it) {
            const int b = (int)(dv[it] >> 8);
            const int p = atomicAdd(&lcur[b], 1);
            el[p] = (dv[it] << 16) | sv[it];
        }
        __syncthreads();

        // 4) coalesced copy-out
        #pragma unroll
        for (int it = 0; it < ITER_A; ++it) {
            const int i = t + it * 256;
            const unsigned packed = el[i];
            const int b = (int)(packed >> 24);           // dst>>8
            const int pin = gbase[b] + (i - bexc[b]);
            if (pin < BCAP) {
                coarse[(size_t)b * BCAP + pin] = packed;
            } else {
                const int o = atomicAdd(&gcnt[NB], 1);
                if (o < OVF_CAP) ovf[o] = packed;
            }
        }
    }
}

// ---------------------------------------------------------------------------
// K2 (pass B): one block per bucket, 512 threads. Fused load+histogram;
// wave-shfl scan (2 barriers vs 16); dst-sort into LDS es[] (scattered
// writes stay in LDS) then stream back to coarse fully coalesced.
// ---------------------------------------------------------------------------
__global__ __launch_bounds__(512) void gat_binsort(
    unsigned* __restrict__ coarse,
    const int* __restrict__ gcnt,
    int* __restrict__ start, int* __restrict__ deg)
{
    __shared__ unsigned el[BCAP];                 // 24.6 KB unsorted
    __shared__ unsigned es[BCAP];                 // 24.6 KB dst-sorted
    __shared__ int hist[256], cur[256];           // 2 KB
    __shared__ int wsum[8];
    const int b    = blockIdx.x;
    const int t    = threadIdx.x;
    const int lane = t & 63;
    const int w    = t >> 6;
    const int nb   = min(gcnt[b], BCAP);

    if (t < 256) hist[t] = 0;
    __syncthreads();

    // fused load + histogram (one pass over the bucket)
    #pragma unroll 4
    for (int i = t; i < nb; i += 512) {
        const unsigned e = coarse[(size_t)b * BCAP + i];
        el[i] = e;
        atomicAdd(&hist[(e >> 16) & 255], 1);
    }
    __syncthreads();

    // wave-shfl exclusive scan over the 256 bins (threads >=256 carry 0)
    const int v = (t < 256) ? hist[t] : 0;
    int x = v;
    #pragma unroll
    for (int off = 1; off < 64; off <<= 1) {
        const int y = __shfl_up(x, off, 64);
        if (lane >= off) x += y;
    }
    if (lane == 63) wsum[w] = x;
    __syncthreads();
    int prefix = 0;
    #pragma unroll
    for (int ww = 0; ww < 8; ++ww)
        if (ww < w) prefix += wsum[ww];       // waves 4..7 sum zeros
    const int excl = x + prefix - v;
    if (t < 256) {
        cur[t] = excl;
        const int n = b * 256 + t;
        if (n < N_NODES) {
            start[n] = b * BCAP + excl;
            deg[n]   = v;
        }
    }
    __syncthreads();

    // dst-sort into LDS (scatter stays on-chip)
    #pragma unroll 4
    for (int i = t; i < nb; i += 512) {
        const unsigned e = el[i];
        const int p = atomicAdd(&cur[(e >> 16) & 255], 1);
        es[p] = e;
    }
    __syncthreads();

    // coalesced linear write-back
    #pragma unroll 4
    for (int i = t; i < nb; i += 512)
        coarse[(size_t)b * BCAP + i] = es[i];
}

// ---------------------------------------------------------------------------
// K3: gather (round-5 / best-known form). 8 lanes/edge (ushort8 = 16B z
// load), 8 edge slots, 16-edge unroll (two independent chains).
// ---------------------------------------------------------------------------
__global__ __launch_bounds__(256) void gat_gather(
    const int* __restrict__ start, const int* __restrict__ deg,
    const unsigned* __restrict__ coarse, const int* __restrict__ gcnt,
    const unsigned* __restrict__ ovf,
    const float* __restrict__ s1, const float* __restrict__ s2,
    const unsigned short* __restrict__ z16,
    float* __restrict__ out)
{
    const int lane = threadIdx.x & 63;
    const int c    = lane & 7;        // feature group: features 8c..8c+7
    const int q    = lane >> 3;       // edge slot 0..7
    const int n    = blockIdx.x * 4 + (threadIdx.x >> 6);
    if (n >= N_NODES) return;

    const int m  = deg[n];
    const int jb = start[n];
    const float s2n = s2[n];                       // includes b_att

    float acc[8] = {0,0,0,0,0,0,0,0};
    int j = 0;
    for (; j + 16 <= m; j += 16) {
        const int srcA = (int)(coarse[jb + j + q] & 0xFFFFu);
        const int srcB = (int)(coarse[jb + j + 8 + q] & 0xFFFFu);
        float aA = s1[srcA] + s2n;
        float aB = s1[srcB] + s2n;
        aA = (aA > 0.f) ? aA : 0.01f * aA;
        aB = (aB > 0.f) ? aB : 0.01f * aB;
        const u16x8 zA = *(const u16x8*)&z16[(size_t)srcA * OUT_DIM + 8 * c];
        const u16x8 zB = *(const u16x8*)&z16[(size_t)srcB * OUT_DIM + 8 * c];
        #pragma unroll
        for (int u = 0; u < 8; ++u) acc[u] += aA * bf16_to_f32(zA[u]);
        #pragma unroll
        for (int u = 0; u < 8; ++u) acc[u] += aB * bf16_to_f32(zB[u]);
    }
    for (; j + 8 <= m; j += 8) {
        const int src = (int)(coarse[jb + j + q] & 0xFFFFu);
        float a = s1[src] + s2n;
        a = (a > 0.f) ? a : 0.01f * a;
        const u16x8 zz = *(const u16x8*)&z16[(size_t)src * OUT_DIM + 8 * c];
        #pragma unroll
        for (int u = 0; u < 8; ++u) acc[u] += a * bf16_to_f32(zz[u]);
    }
    if (q < m - j) {
        const int src = (int)(coarse[jb + j + q] & 0xFFFFu);
        float a = s1[src] + s2n;
        a = (a > 0.f) ? a : 0.01f * a;
        const u16x8 zz = *(const u16x8*)&z16[(size_t)src * OUT_DIM + 8 * c];
        #pragma unroll
        for (int u = 0; u < 8; ++u) acc[u] += a * bf16_to_f32(zz[u]);
    }

    // self-service overflow (expected 0)
    const int novf = min(gcnt[NB], OVF_CAP);
    for (int base = 0; base < novf; base += 8) {
        const int idx = base + q;
        const unsigned packed = (idx < novf) ? ovf[idx] : 0xFFFFFFFFu;
        const bool valid = (idx < novf) && ((packed >> 16) == (unsigned)n);
        const int src = valid ? (int)(packed & 0xFFFFu) : 0;
        float a = s1[src] + s2n;
        a = (a > 0.f) ? a : 0.01f * a;
        a = valid ? a : 0.f;
        const u16x8 zz = *(const u16x8*)&z16[(size_t)src * OUT_DIM + 8 * c];
        #pragma unroll
        for (int u = 0; u < 8; ++u) acc[u] += a * bf16_to_f32(zz[u]);
    }

    // combine the 8 edge slots (slot index in lane bits 3..5)
    #pragma unroll
    for (int u = 0; u < 8; ++u) {
        acc[u] += __shfl_xor(acc[u], 8, 64);
        acc[u] += __shfl_xor(acc[u], 16, 64);
        acc[u] += __shfl_xor(acc[u], 32, 64);
    }

    if (q == 0) {
        float4 lo = make_float4(acc[0], acc[1], acc[2], acc[3]);
        float4 hi = make_float4(acc[4], acc[5], acc[6], acc[7]);
        *(float4*)&out[(size_t)n * OUT_DIM + 8 * c]     = lo;
        *(float4*)&out[(size_t)n * OUT_DIM + 8 * c + 4] = hi;
    }
}

extern "C" void kernel_launch(void* const* d_in, const int* in_sizes, int n_in,
                              void* d_out, int out_size, void* d_ws, size_t ws_size,
                              hipStream_t stream)
{
    const int*   adj  = (const int*)  d_in[0];   // (2, E)
    const float* h    = (const float*)d_in[1];   // (N, 128)
    const float* Wfc  = (const float*)d_in[2];   // (64, 128)
    const float* bfc  = (const float*)d_in[3];   // (64,)
    const float* Watt = (const float*)d_in[4];   // (1, 128)
    const float* batt = (const float*)d_in[5];   // (1,)
    float* out = (float*)d_out;                  // (N, 64)

    // ws layout (12.1 MB): z16[N*64] u16 | s1[N] | s2[N] | start[N] | deg[N]
    // | gcnt[NB+1] ([NB]=ovf count) | ovf[OVF_CAP] u32 | coarse[NB*BCAP] u32
    unsigned short* z16 = (unsigned short*)d_ws;
    float* s1    = (float*)(z16 + (size_t)N_NODES * OUT_DIM);
    float* s2    = s1 + N_NODES;
    int*   start = (int*)(s2 + N_NODES);
    int*   deg   = start + N_NODES;
    int*   gcnt  = deg + N_NODES;
    unsigned* ovf    = (unsigned*)(gcnt + NB + 1);
    unsigned* coarse = ovf + OVF_CAP;

    hipMemsetAsync(gcnt, 0, (NB + 1) * sizeof(int), stream);

    gat_fc_scatter<<<NBLK_FC + NBLK_SA, 256, 0, stream>>>(
        h, Wfc, bfc, Watt, batt, adj, z16, s1, s2, gcnt, coarse, ovf);
    gat_binsort<<<NB, 512, 0, stream>>>(coarse, gcnt, start, deg);
    gat_gather<<<(N_NODES + 3) / 4, 256, 0, stream>>>(
        start, deg, coarse, gcnt, ovf, s1, s2, z16, out);
}